// Round 12
// baseline (387.665 us; speedup 1.0000x reference)
//
#include <hip/hip_runtime.h>

#define Bn 2
#define Hn 16
#define Tn 2048
#define Sn 2048
#define Wd 1024
#define Dh 64
#define NBLK 512

typedef __attribute__((ext_vector_type(8))) short s16x8;
typedef __attribute__((ext_vector_type(4))) short s16x4;
typedef __attribute__((ext_vector_type(4))) float f32x4;
typedef __attribute__((ext_vector_type(4))) unsigned u32x4;

#define MFMA(a, b, c) __builtin_amdgcn_mfma_f32_16x16x32_bf16((a), (b), (c), 0, 0, 0)

__device__ __forceinline__ s16x8 ld8(const short* p) { return *(const s16x8*)p; }

// fp32 -> bf16 round-to-nearest-even
__device__ __forceinline__ short f2bf(float f) {
    unsigned u = __builtin_bit_cast(unsigned, f);
    u += 0x7FFFu + ((u >> 16) & 1u);
    return (short)(u >> 16);
}

// pack 2 f32 -> 2 bf16 (RNE) in one instruction
__device__ __forceinline__ unsigned cvtpk(float lo, float hi) {
    unsigned r;
    asm("v_cvt_pk_bf16_f32 %0, %1, %2" : "=v"(r) : "v"(lo), "v"(hi));
    return r;
}

// async global->LDS, 16B/lane: LDS dest = wave-uniform base + lane*16
__device__ __forceinline__ void gl_lds(const short* g, short* lds) {
    __builtin_amdgcn_global_load_lds(
        (const __attribute__((address_space(1))) void*)g,
        (__attribute__((address_space(3))) void*)lds, 16, 0, 0);
}

// Barrier state init (runs just before fused on the same stream; stream order
// guarantees completion + coherence at the kernel boundary).  Immune to the
// harness's workspace re-poisoning.
__global__ void binit(unsigned* bar) { bar[0] = 0u; bar[1] = 0u; }

// Hand-rolled co-resident grid barrier (hipLaunchCooperativeKernel never
// executed under the harness's graph capture -- R10/R11 output == memset
// zeros).  Safe because occupancy is exact: 512 blocks = 2/CU x 256 CU
// (launch_bounds(512,4) -> <=128 VGPR -> 4 waves/SIMD; 64KB LDS -> 2/CU).
// Release fence (s_waitcnt + buffer_wbl2: L2 writeback) before arrival;
// generation-protocol arrive/spin via device-scope atomics; acquire fence
// (buffer_inv) by every wave after release from the barrier.  Watchdog-
// bounded spin: a co-residency violation fails visibly, never hangs.
__device__ __forceinline__ void gbar(unsigned* bar) {
    __syncthreads();                  // all waves drain their VMEM (compiler
                                      // emits vmcnt(0) before s_barrier)
    if (threadIdx.x == 0) {
        __builtin_amdgcn_fence(__ATOMIC_RELEASE, "agent");
        unsigned g = __hip_atomic_load(&bar[1], __ATOMIC_ACQUIRE,
                                       __HIP_MEMORY_SCOPE_AGENT);
        unsigned arr = __hip_atomic_fetch_add(&bar[0], 1u, __ATOMIC_ACQ_REL,
                                              __HIP_MEMORY_SCOPE_AGENT);
        if (arr == NBLK - 1u) {
            __hip_atomic_store(&bar[0], 0u, __ATOMIC_RELAXED,
                               __HIP_MEMORY_SCOPE_AGENT);
            __hip_atomic_fetch_add(&bar[1], 1u, __ATOMIC_RELEASE,
                                   __HIP_MEMORY_SCOPE_AGENT);
        } else {
            long spins = 0;
            while (__hip_atomic_load(&bar[1], __ATOMIC_ACQUIRE,
                                     __HIP_MEMORY_SCOPE_AGENT) == g) {
                __builtin_amdgcn_s_sleep(2);
                if (++spins > (1L << 26)) break;   // ~seconds; fail visibly
            }
        }
    }
    __syncthreads();
    __builtin_amdgcn_fence(__ATOMIC_ACQUIRE, "agent");
}

// ---------------------------------------------------------------------------
// Single fused kernel: prep -> gbar -> attn -> gbar -> proj.
// Grid 512 x 512 thr, 64KB LDS union, launch_bounds(512,4) -> exactly
// 2 blocks/CU co-resident (16 waves/CU).  Fusion removes 2 kernel boundaries
// and keeps packed K/V and the attn output L2/L3-warm into their consumers.
// Phase bodies are byte-identical to the R8 bench-verified kernels.
// ---------------------------------------------------------------------------
__global__ __launch_bounds__(512, 4) void fused(
    const float* __restrict__ x,  const float* __restrict__ ck,
    const float* __restrict__ cv, const float* __restrict__ wp,
    const float* __restrict__ bias,
    short* __restrict__ kp, short* __restrict__ vp, short* __restrict__ wb,
    short* __restrict__ am, float* __restrict__ out, unsigned* __restrict__ bar)
{
    __shared__ alignas(16) short U[32768];   // 64 KB union for all phases

    const int tid  = threadIdx.x;
    const int bid  = blockIdx.x;
    const int w    = tid >> 6;               // 0..7
    const int l    = tid & 63;
    const int quad = l >> 4;
    const int l16  = l & 15;

    // ===================== P1: prep =====================
    for (int task = bid; task < 2304; task += 512) {
        __syncthreads();                     // protect U reuse across tasks
        if (task < 2048) {
            const int isV = task >> 10;      // 0 = kpack, 1 = vpack
            const int c   = task & 1023;
            const int bh = c >> 5, sc = c & 31;
            const int b = bh >> 4, h = bh & 15;
            const float* src = (isV ? cv : ck) + (size_t)(b * Sn + sc * 64) * Wd + h * Dh;
#pragma unroll
            for (int i = 0; i < 2; ++i) {
                int f = i * 512 + tid, sr = f >> 4, c4 = f & 15;
                float4 v = *(const float4*)(src + (size_t)sr * Wd + c4 * 4);
                s16x4 o;
                o[0] = f2bf(v.x); o[1] = f2bf(v.y); o[2] = f2bf(v.z); o[3] = f2bf(v.w);
                *(s16x4*)&U[sr * 72 + c4 * 4] = o;
            }
            __syncthreads();
            if (tid < 256) {
                const int rt = tid >> 6;     // 0..3
                if (!isV) {
                    size_t base = ((size_t)((bh * 128 + sc * 4 + rt) * 2)) * 512 + l * 8;
                    *(s16x8*)(kp + base)       = *(const s16x8*)&U[(rt * 16 + l16) * 72 + quad * 8];
                    *(s16x8*)(kp + base + 512) = *(const s16x8*)&U[(rt * 16 + l16) * 72 + 32 + quad * 8];
                } else {
#pragma unroll
                    for (int g = 0; g < 2; ++g) {
                        s16x8 o;
#pragma unroll
                        for (int j = 0; j < 8; ++j) {
                            int s = 32 * g + 16 * (j >> 2) + quad * 4 + (j & 3);
                            o[j] = U[s * 72 + rt * 16 + l16];
                        }
                        *(s16x8*)(vp + ((size_t)((bh * 32 + sc) * 8 + rt * 2 + g)) * 512 + l * 8) = o;
                    }
                }
            }
        } else {
            int i = ((task - 2048) * 512 + tid) * 8;
            float4 a = *(const float4*)(wp + i);
            float4 b2 = *(const float4*)(wp + i + 4);
            s16x8 o;
            o[0] = f2bf(a.x); o[1] = f2bf(a.y); o[2] = f2bf(a.z); o[3] = f2bf(a.w);
            o[4] = f2bf(b2.x); o[5] = f2bf(b2.y); o[6] = f2bf(b2.z); o[7] = f2bf(b2.w);
            *(s16x8*)(wb + i) = o;
        }
    }
    gbar(bar);

    // ===================== P2: attn =====================
    {
        short* const KsB = U;                // [sb*2+pr][4096] (32 KB)
        short* const VsB = U + 16384;        // [sb*2+pr][4096] (32 KB)

        const int wq = w & 3;                // q subtile (32 rows)
        const int pr = w >> 2;               // s parity

        const int bh = bid & 31;             // blk%8 = bh%8 -> XCD locality
        const int qt = bid >> 5;
        const int b  = bh >> 4, h = bh & 15;

        const int qrow0 = qt * 128 + wq * 32;

        const short* kp_h = kp + (size_t)bh * 131072;
        const short* vp_h = vp + (size_t)bh * 131072;

        // prologue: stage super-pair 0 (chunks 0,1) into superbuf 0
        gl_lds(kp_h + ((size_t)(0 * 8 + w)) * 512 + l * 8, KsB + 0 * 4096 + w * 512);
        gl_lds(vp_h + ((size_t)(0 * 8 + w)) * 512 + l * 8, VsB + 0 * 4096 + w * 512);
        gl_lds(kp_h + ((size_t)(1 * 8 + w)) * 512 + l * 8, KsB + 1 * 4096 + w * 512);
        gl_lds(vp_h + ((size_t)(1 * 8 + w)) * 512 + l * 8, VsB + 1 * 4096 + w * 512);

        const float SQ = 0.125f * 1.4426950408889634f;
        s16x8 aq[2][2];
#pragma unroll
        for (int mi = 0; mi < 2; ++mi)
#pragma unroll
            for (int c = 0; c < 2; ++c) {
                const float* p = x + (size_t)(b * Tn + qrow0 + mi * 16 + l16) * Wd
                                   + h * Dh + c * 32 + quad * 8;
                float4 a = ((const float4*)p)[0], bb = ((const float4*)p)[1];
                s16x8 o;
                o[0] = f2bf(a.x * SQ); o[1] = f2bf(a.y * SQ); o[2] = f2bf(a.z * SQ); o[3] = f2bf(a.w * SQ);
                o[4] = f2bf(bb.x * SQ); o[5] = f2bf(bb.y * SQ); o[6] = f2bf(bb.z * SQ); o[7] = f2bf(bb.w * SQ);
                aq[mi][c] = o;
            }

        f32x4 oacc[2][4], dnacc[2];
#pragma unroll
        for (int mi = 0; mi < 2; ++mi) {
#pragma unroll
            for (int nt = 0; nt < 4; ++nt) {
                oacc[mi][nt][0] = 0.f; oacc[mi][nt][1] = 0.f;
                oacc[mi][nt][2] = 0.f; oacc[mi][nt][3] = 0.f;
            }
            dnacc[mi][0] = 0.f; dnacc[mi][1] = 0.f;
            dnacc[mi][2] = 0.f; dnacc[mi][3] = 0.f;
        }

        s16x8 ones;
#pragma unroll
        for (int j = 0; j < 8; ++j) ones[j] = (short)0x3F80;   // bf16 1.0

        const f32x4 z = {0.f, 0.f, 0.f, 0.f};
        const int NSIT = Sn / 128;           // 16 super-iters (2 chunks each)

        asm volatile("s_waitcnt vmcnt(0)" ::: "memory");
        __syncthreads();

        for (int t = 0; t < NSIT; ++t) {
            const int sb = t & 1;

            if (t + 1 < NSIT) {
                const size_t c0 = (size_t)(2 * t + 2) * 8;
                gl_lds(kp_h + (c0 + w) * 512 + l * 8,     KsB + ((sb ^ 1) * 2 + 0) * 4096 + w * 512);
                gl_lds(vp_h + (c0 + w) * 512 + l * 8,     VsB + ((sb ^ 1) * 2 + 0) * 4096 + w * 512);
                gl_lds(kp_h + (c0 + 8 + w) * 512 + l * 8, KsB + ((sb ^ 1) * 2 + 1) * 4096 + w * 512);
                gl_lds(vp_h + (c0 + 8 + w) * 512 + l * 8, VsB + ((sb ^ 1) * 2 + 1) * 4096 + w * 512);
            }

            const short* Kb = KsB + (sb * 2 + pr) * 4096;
            const short* Vb = VsB + (sb * 2 + pr) * 4096;

            s16x8 kf[4][2];
#pragma unroll
            for (int sj = 0; sj < 4; ++sj)
#pragma unroll
                for (int g = 0; g < 2; ++g)
                    kf[sj][g] = *(const s16x8*)&Kb[(sj * 2 + g) * 512 + l * 8];

            f32x4 sc[2][4];
            __builtin_amdgcn_s_setprio(1);
#pragma unroll
            for (int sj = 0; sj < 4; ++sj)
#pragma unroll
                for (int mi = 0; mi < 2; ++mi) {
                    sc[mi][sj] = MFMA(kf[sj][0], aq[mi][0], z);
                    sc[mi][sj] = MFMA(kf[sj][1], aq[mi][1], sc[mi][sj]);
                }
            __builtin_amdgcn_s_setprio(0);

            s16x8 ap[2][2];
#pragma unroll
            for (int mi = 0; mi < 2; ++mi) {
                float ex[4][4];
#pragma unroll
                for (int sj = 0; sj < 4; ++sj)
#pragma unroll
                    for (int r = 0; r < 4; ++r)
                        ex[sj][r] = __builtin_amdgcn_exp2f(sc[mi][sj][r]);
#pragma unroll
                for (int g = 0; g < 2; ++g) {
                    u32x4 pk;
                    pk[0] = cvtpk(ex[2 * g][0],     ex[2 * g][1]);
                    pk[1] = cvtpk(ex[2 * g][2],     ex[2 * g][3]);
                    pk[2] = cvtpk(ex[2 * g + 1][0], ex[2 * g + 1][1]);
                    pk[3] = cvtpk(ex[2 * g + 1][2], ex[2 * g + 1][3]);
                    ap[mi][g] = __builtin_bit_cast(s16x8, pk);
                }
            }

            s16x8 vf[4][2];
#pragma unroll
            for (int nt = 0; nt < 4; ++nt)
#pragma unroll
                for (int g = 0; g < 2; ++g)
                    vf[nt][g] = *(const s16x8*)&Vb[(nt * 2 + g) * 512 + l * 8];

            __builtin_amdgcn_s_setprio(1);
#pragma unroll
            for (int mi = 0; mi < 2; ++mi) {
                dnacc[mi] = MFMA(ap[mi][0], ones, dnacc[mi]);
                dnacc[mi] = MFMA(ap[mi][1], ones, dnacc[mi]);
            }
#pragma unroll
            for (int mi = 0; mi < 2; ++mi)
#pragma unroll
                for (int nt = 0; nt < 4; ++nt) {
                    oacc[mi][nt] = MFMA(ap[mi][0], vf[nt][0], oacc[mi][nt]);
                    oacc[mi][nt] = MFMA(ap[mi][1], vf[nt][1], oacc[mi][nt]);
                }
            __builtin_amdgcn_s_setprio(0);

            asm volatile("s_waitcnt vmcnt(0)" ::: "memory");
            __syncthreads();
        }

        // combine parity partners via LDS (reuse K/V buffers)
        float* ob = (float*)U;               // 128 q x 64 d fp32 = 32 KB
        float* db = (float*)(U + 16384);     // 128 q fp32
        if (pr == 1) {
#pragma unroll
            for (int mi = 0; mi < 2; ++mi) {
#pragma unroll
                for (int r = 0; r < 4; ++r) {
                    int ql = wq * 32 + mi * 16 + quad * 4 + r;
#pragma unroll
                    for (int nt = 0; nt < 4; ++nt)
                        ob[ql * 64 + nt * 16 + l16] = oacc[mi][nt][r];
                    if (l16 == 0) db[ql] = dnacc[mi][r];
                }
            }
        }
        __syncthreads();
        if (pr == 0) {
#pragma unroll
            for (int mi = 0; mi < 2; ++mi)
#pragma unroll
                for (int r = 0; r < 4; ++r) {
                    int ql = wq * 32 + mi * 16 + quad * 4 + r;
                    float inv = 1.0f / (dnacc[mi][r] + db[ql]);
                    int t = qrow0 + mi * 16 + quad * 4 + r;
#pragma unroll
                    for (int nt = 0; nt < 4; ++nt) {
                        float v = oacc[mi][nt][r] + ob[ql * 64 + nt * 16 + l16];
                        am[(size_t)(b * Tn + t) * Wd + h * Dh + nt * 16 + l16] = f2bf(v * inv);
                    }
                }
        }
    }
    gbar(bar);

    // ===================== P3: proj =====================
    {
        short* const AsB = U;                // [2][128*72] = 36,864 B
        short* const BsB = U + 18432;        // [2][64*72]  = 18,432 B

        const int bn = bid & 15;             // 16 n-tiles
        const int bm = bid >> 4;             // 32 m-tiles
        const int m0 = bm * 128;
        const int n0 = bn * 64;
        const int wm = (w & 3) * 32;         // wave m-offset (4 m-waves)
        const int wn = (w >> 2) * 32;        // wave n-offset (2 n-waves)

        const int rr = tid >> 3;             // staging row 0..63
        const int sg = tid & 7;              // 16B segment 0..7 (BK=64)

        f32x4 acc[2][2];
#pragma unroll
        for (int mi = 0; mi < 2; ++mi)
#pragma unroll
            for (int nt = 0; nt < 2; ++nt) {
                acc[mi][nt][0] = 0.f; acc[mi][nt][1] = 0.f;
                acc[mi][nt][2] = 0.f; acc[mi][nt][3] = 0.f;
            }

        // prologue: stage k-chunk 0 into buffer 0
        s16x8 ra0 = ld8(am + (size_t)(m0 + rr) * Wd + sg * 8);
        s16x8 ra1 = ld8(am + (size_t)(m0 + 64 + rr) * Wd + sg * 8);
        s16x8 rb  = ld8(wb + (size_t)(n0 + rr) * Wd + sg * 8);
        *(s16x8*)&AsB[rr * 72 + sg * 8]        = ra0;
        *(s16x8*)&AsB[(rr + 64) * 72 + sg * 8] = ra1;
        *(s16x8*)&BsB[rr * 72 + sg * 8]        = rb;
        __syncthreads();

        for (int k0 = 0; k0 < Wd; k0 += 64) {
            const int p = (k0 >> 6) & 1;
            short* Asp = AsB + p * 9216;
            short* Bsp = BsB + p * 4608;

            if (k0 + 64 < Wd) {
                ra0 = ld8(am + (size_t)(m0 + rr) * Wd + k0 + 64 + sg * 8);
                ra1 = ld8(am + (size_t)(m0 + 64 + rr) * Wd + k0 + 64 + sg * 8);
                rb  = ld8(wb + (size_t)(n0 + rr) * Wd + k0 + 64 + sg * 8);
            }

            s16x8 a[2][2], bw[2][2];
#pragma unroll
            for (int mi = 0; mi < 2; ++mi)
#pragma unroll
                for (int ks = 0; ks < 2; ++ks)
                    a[mi][ks] = *(const s16x8*)&Asp[(wm + mi * 16 + l16) * 72 + ks * 32 + quad * 8];
#pragma unroll
            for (int nt = 0; nt < 2; ++nt)
#pragma unroll
                for (int ks = 0; ks < 2; ++ks)
                    bw[nt][ks] = *(const s16x8*)&Bsp[(wn + nt * 16 + l16) * 72 + ks * 32 + quad * 8];

            __builtin_amdgcn_s_setprio(1);
#pragma unroll
            for (int mi = 0; mi < 2; ++mi)
#pragma unroll
                for (int nt = 0; nt < 2; ++nt) {
                    acc[mi][nt] = MFMA(a[mi][0], bw[nt][0], acc[mi][nt]);
                    acc[mi][nt] = MFMA(a[mi][1], bw[nt][1], acc[mi][nt]);
                }
            __builtin_amdgcn_s_setprio(0);

            if (k0 + 64 < Wd) {
                short* Asn = AsB + (p ^ 1) * 9216;
                short* Bsn = BsB + (p ^ 1) * 4608;
                *(s16x8*)&Asn[rr * 72 + sg * 8]        = ra0;
                *(s16x8*)&Asn[(rr + 64) * 72 + sg * 8] = ra1;
                *(s16x8*)&Bsn[rr * 72 + sg * 8]        = rb;
            }
            __syncthreads();
        }

#pragma unroll
        for (int nt = 0; nt < 2; ++nt) {
            float bv = bias[n0 + wn + nt * 16 + l16];
#pragma unroll
            for (int mi = 0; mi < 2; ++mi)
#pragma unroll
                for (int r = 0; r < 4; ++r)
                    out[(size_t)(m0 + wm + mi * 16 + quad * 4 + r) * Wd + n0 + wn + nt * 16 + l16] =
                        acc[mi][nt][r] + bv;
        }
    }
}

extern "C" void kernel_launch(void* const* d_in, const int* in_sizes, int n_in,
                              void* d_out, int out_size, void* d_ws, size_t ws_size,
                              hipStream_t stream) {
    const float* x  = (const float*)d_in[0];   // [2,2048,1024] fp32
    const float* ck = (const float*)d_in[1];   // [2,2048,1024] fp32
    const float* cv = (const float*)d_in[2];   // [2,2048,1024] fp32
    const float* wp = (const float*)d_in[3];   // [1024,1024]   fp32
    const float* bp = (const float*)d_in[4];   // [1024]        fp32

    const int nX = Bn * Tn * Wd;   // 4,194,304
    const int nW = Wd * Wd;        // 1,048,576

    short* kpb = (short*)d_ws;     // 8 MB  (K, MFMA A-frag packed)
    short* vpb = kpb + nX;         // 8 MB  (V^T, MFMA B-frag packed + s-perm)
    short* wbb = vpb + nX;         // 2 MB  (Wp bf16, row-major)
    short* amb = wbb + nW;         // 8 MB  (attention output, bf16)
    unsigned* bar = (unsigned*)(amb + nX);   // 8 B barrier state
    float* op  = (float*)d_out;

    binit<<<dim3(1), dim3(1), 0, stream>>>(bar);
    fused<<<dim3(NBLK), dim3(512), 0, stream>>>(
        x, ck, cv, wp, bp, kpb, vpb, wbb, amb, op, bar);
}

// Round 13
// 290.777 us; speedup vs baseline: 1.3332x; 1.3332x over previous
//
#include <hip/hip_runtime.h>

#define Bn 2
#define Hn 16
#define Tn 2048
#define Sn 2048
#define Wd 1024
#define Dh 64
#define NBLK 512

typedef __attribute__((ext_vector_type(8))) short s16x8;
typedef __attribute__((ext_vector_type(4))) short s16x4;
typedef __attribute__((ext_vector_type(4))) float f32x4;
typedef __attribute__((ext_vector_type(4))) unsigned u32x4;

#define MFMA(a, b, c) __builtin_amdgcn_mfma_f32_16x16x32_bf16((a), (b), (c), 0, 0, 0)

__device__ __forceinline__ s16x8 ld8(const short* p) { return *(const s16x8*)p; }

// fp32 -> bf16 round-to-nearest-even
__device__ __forceinline__ short f2bf(float f) {
    unsigned u = __builtin_bit_cast(unsigned, f);
    u += 0x7FFFu + ((u >> 16) & 1u);
    return (short)(u >> 16);
}

// pack 2 f32 -> 2 bf16 (RNE) in one instruction
__device__ __forceinline__ unsigned cvtpk(float lo, float hi) {
    unsigned r;
    asm("v_cvt_pk_bf16_f32 %0, %1, %2" : "=v"(r) : "v"(lo), "v"(hi));
    return r;
}

// async global->LDS, 16B/lane: LDS dest = wave-uniform base + lane*16
__device__ __forceinline__ void gl_lds(const short* g, short* lds) {
    __builtin_amdgcn_global_load_lds(
        (const __attribute__((address_space(1))) void*)g,
        (__attribute__((address_space(3))) void*)lds, 16, 0, 0);
}

// Barrier state init (runs just before fused on the same stream; stream order
// guarantees completion + coherence at the kernel boundary).
__global__ void binit(unsigned* bar) { bar[0] = 0u; bar[1] = 0u; }

// Co-resident grid barrier, R13 fix: R12's spin used ACQUIRE loads at agent
// scope -- the AMDGPU memory model emits buffer_inv (full L1/L2 invalidate)
// PER POLL, so ~511 spinning blocks storm the fabric with cache invalidates
// (R12: MfmaUtil 6%, 80% idle).  Correct protocol: ONE release fence before
// arrival, RELAXED fetch_add / polls (plain loads, no cache ops), RELEASE
// store on the generation bump, and ONE trailing acquire fence (fence after
// relaxed load = synchronizes-with).  Cache-maintenance ops: 2 per kernel,
// not 2 per poll.  Safe: 512 blocks = 2/CU x 256 CU exactly co-resident
// (launch_bounds(512,4), 64KB LDS).  Bounded spin -> fails visibly, no hang.
__device__ __forceinline__ void gbar(unsigned* bar) {
    __syncthreads();
    if (threadIdx.x == 0) {
        __builtin_amdgcn_fence(__ATOMIC_RELEASE, "agent");
        unsigned g = __hip_atomic_load(&bar[1], __ATOMIC_RELAXED,
                                       __HIP_MEMORY_SCOPE_AGENT);
        unsigned arr = __hip_atomic_fetch_add(&bar[0], 1u, __ATOMIC_RELAXED,
                                              __HIP_MEMORY_SCOPE_AGENT);
        if (arr == NBLK - 1u) {
            __hip_atomic_store(&bar[0], 0u, __ATOMIC_RELAXED,
                               __HIP_MEMORY_SCOPE_AGENT);
            __hip_atomic_store(&bar[1], g + 1u, __ATOMIC_RELEASE,
                               __HIP_MEMORY_SCOPE_AGENT);
        } else {
            long spins = 0;
            while (__hip_atomic_load(&bar[1], __ATOMIC_RELAXED,
                                     __HIP_MEMORY_SCOPE_AGENT) == g) {
                __builtin_amdgcn_s_sleep(8);
                if (++spins > (1L << 24)) break;   // fail visibly, never hang
            }
        }
    }
    __syncthreads();
    __builtin_amdgcn_fence(__ATOMIC_ACQUIRE, "agent");
}

// ---------------------------------------------------------------------------
// Single fused kernel: prep -> gbar -> attn -> gbar -> proj.
// Grid 512 x 512 thr, 64KB LDS union, launch_bounds(512,4) -> exactly
// 2 blocks/CU co-resident (16 waves/CU).  Fusion removes 2 kernel boundaries
// and keeps packed K/V and the attn output L2/L3-warm into their consumers.
// Phase bodies are byte-identical to the R8 bench-verified kernels.
// ---------------------------------------------------------------------------
__global__ __launch_bounds__(512, 4) void fused(
    const float* __restrict__ x,  const float* __restrict__ ck,
    const float* __restrict__ cv, const float* __restrict__ wp,
    const float* __restrict__ bias,
    short* __restrict__ kp, short* __restrict__ vp, short* __restrict__ wb,
    short* __restrict__ am, float* __restrict__ out, unsigned* __restrict__ bar)
{
    __shared__ alignas(16) short U[32768];   // 64 KB union for all phases

    const int tid  = threadIdx.x;
    const int bid  = blockIdx.x;
    const int w    = tid >> 6;               // 0..7
    const int l    = tid & 63;
    const int quad = l >> 4;
    const int l16  = l & 15;

    // ===================== P1: prep =====================
    for (int task = bid; task < 2304; task += 512) {
        __syncthreads();                     // protect U reuse across tasks
        if (task < 2048) {
            const int isV = task >> 10;      // 0 = kpack, 1 = vpack
            const int c   = task & 1023;
            const int bh = c >> 5, sc = c & 31;
            const int b = bh >> 4, h = bh & 15;
            const float* src = (isV ? cv : ck) + (size_t)(b * Sn + sc * 64) * Wd + h * Dh;
#pragma unroll
            for (int i = 0; i < 2; ++i) {
                int f = i * 512 + tid, sr = f >> 4, c4 = f & 15;
                float4 v = *(const float4*)(src + (size_t)sr * Wd + c4 * 4);
                s16x4 o;
                o[0] = f2bf(v.x); o[1] = f2bf(v.y); o[2] = f2bf(v.z); o[3] = f2bf(v.w);
                *(s16x4*)&U[sr * 72 + c4 * 4] = o;
            }
            __syncthreads();
            if (tid < 256) {
                const int rt = tid >> 6;     // 0..3
                if (!isV) {
                    size_t base = ((size_t)((bh * 128 + sc * 4 + rt) * 2)) * 512 + l * 8;
                    *(s16x8*)(kp + base)       = *(const s16x8*)&U[(rt * 16 + l16) * 72 + quad * 8];
                    *(s16x8*)(kp + base + 512) = *(const s16x8*)&U[(rt * 16 + l16) * 72 + 32 + quad * 8];
                } else {
#pragma unroll
                    for (int g = 0; g < 2; ++g) {
                        s16x8 o;
#pragma unroll
                        for (int j = 0; j < 8; ++j) {
                            int s = 32 * g + 16 * (j >> 2) + quad * 4 + (j & 3);
                            o[j] = U[s * 72 + rt * 16 + l16];
                        }
                        *(s16x8*)(vp + ((size_t)((bh * 32 + sc) * 8 + rt * 2 + g)) * 512 + l * 8) = o;
                    }
                }
            }
        } else {
            int i = ((task - 2048) * 512 + tid) * 8;
            float4 a = *(const float4*)(wp + i);
            float4 b2 = *(const float4*)(wp + i + 4);
            s16x8 o;
            o[0] = f2bf(a.x); o[1] = f2bf(a.y); o[2] = f2bf(a.z); o[3] = f2bf(a.w);
            o[4] = f2bf(b2.x); o[5] = f2bf(b2.y); o[6] = f2bf(b2.z); o[7] = f2bf(b2.w);
            *(s16x8*)(wb + i) = o;
        }
    }
    gbar(bar);

    // ===================== P2: attn =====================
    {
        short* const KsB = U;                // [sb*2+pr][4096] (32 KB)
        short* const VsB = U + 16384;        // [sb*2+pr][4096] (32 KB)

        const int wq = w & 3;                // q subtile (32 rows)
        const int pr = w >> 2;               // s parity

        const int bh = bid & 31;             // blk%8 = bh%8 -> XCD locality
        const int qt = bid >> 5;
        const int b  = bh >> 4, h = bh & 15;

        const int qrow0 = qt * 128 + wq * 32;

        const short* kp_h = kp + (size_t)bh * 131072;
        const short* vp_h = vp + (size_t)bh * 131072;

        // prologue: stage super-pair 0 (chunks 0,1) into superbuf 0
        gl_lds(kp_h + ((size_t)(0 * 8 + w)) * 512 + l * 8, KsB + 0 * 4096 + w * 512);
        gl_lds(vp_h + ((size_t)(0 * 8 + w)) * 512 + l * 8, VsB + 0 * 4096 + w * 512);
        gl_lds(kp_h + ((size_t)(1 * 8 + w)) * 512 + l * 8, KsB + 1 * 4096 + w * 512);
        gl_lds(vp_h + ((size_t)(1 * 8 + w)) * 512 + l * 8, VsB + 1 * 4096 + w * 512);

        const float SQ = 0.125f * 1.4426950408889634f;
        s16x8 aq[2][2];
#pragma unroll
        for (int mi = 0; mi < 2; ++mi)
#pragma unroll
            for (int c = 0; c < 2; ++c) {
                const float* p = x + (size_t)(b * Tn + qrow0 + mi * 16 + l16) * Wd
                                   + h * Dh + c * 32 + quad * 8;
                float4 a = ((const float4*)p)[0], bb = ((const float4*)p)[1];
                s16x8 o;
                o[0] = f2bf(a.x * SQ); o[1] = f2bf(a.y * SQ); o[2] = f2bf(a.z * SQ); o[3] = f2bf(a.w * SQ);
                o[4] = f2bf(bb.x * SQ); o[5] = f2bf(bb.y * SQ); o[6] = f2bf(bb.z * SQ); o[7] = f2bf(bb.w * SQ);
                aq[mi][c] = o;
            }

        f32x4 oacc[2][4], dnacc[2];
#pragma unroll
        for (int mi = 0; mi < 2; ++mi) {
#pragma unroll
            for (int nt = 0; nt < 4; ++nt) {
                oacc[mi][nt][0] = 0.f; oacc[mi][nt][1] = 0.f;
                oacc[mi][nt][2] = 0.f; oacc[mi][nt][3] = 0.f;
            }
            dnacc[mi][0] = 0.f; dnacc[mi][1] = 0.f;
            dnacc[mi][2] = 0.f; dnacc[mi][3] = 0.f;
        }

        s16x8 ones;
#pragma unroll
        for (int j = 0; j < 8; ++j) ones[j] = (short)0x3F80;   // bf16 1.0

        const f32x4 z = {0.f, 0.f, 0.f, 0.f};
        const int NSIT = Sn / 128;           // 16 super-iters (2 chunks each)

        asm volatile("s_waitcnt vmcnt(0)" ::: "memory");
        __syncthreads();

        for (int t = 0; t < NSIT; ++t) {
            const int sb = t & 1;

            if (t + 1 < NSIT) {
                const size_t c0 = (size_t)(2 * t + 2) * 8;
                gl_lds(kp_h + (c0 + w) * 512 + l * 8,     KsB + ((sb ^ 1) * 2 + 0) * 4096 + w * 512);
                gl_lds(vp_h + (c0 + w) * 512 + l * 8,     VsB + ((sb ^ 1) * 2 + 0) * 4096 + w * 512);
                gl_lds(kp_h + (c0 + 8 + w) * 512 + l * 8, KsB + ((sb ^ 1) * 2 + 1) * 4096 + w * 512);
                gl_lds(vp_h + (c0 + 8 + w) * 512 + l * 8, VsB + ((sb ^ 1) * 2 + 1) * 4096 + w * 512);
            }

            const short* Kb = KsB + (sb * 2 + pr) * 4096;
            const short* Vb = VsB + (sb * 2 + pr) * 4096;

            s16x8 kf[4][2];
#pragma unroll
            for (int sj = 0; sj < 4; ++sj)
#pragma unroll
                for (int g = 0; g < 2; ++g)
                    kf[sj][g] = *(const s16x8*)&Kb[(sj * 2 + g) * 512 + l * 8];

            f32x4 sc[2][4];
            __builtin_amdgcn_s_setprio(1);
#pragma unroll
            for (int sj = 0; sj < 4; ++sj)
#pragma unroll
                for (int mi = 0; mi < 2; ++mi) {
                    sc[mi][sj] = MFMA(kf[sj][0], aq[mi][0], z);
                    sc[mi][sj] = MFMA(kf[sj][1], aq[mi][1], sc[mi][sj]);
                }
            __builtin_amdgcn_s_setprio(0);

            s16x8 ap[2][2];
#pragma unroll
            for (int mi = 0; mi < 2; ++mi) {
                float ex[4][4];
#pragma unroll
                for (int sj = 0; sj < 4; ++sj)
#pragma unroll
                    for (int r = 0; r < 4; ++r)
                        ex[sj][r] = __builtin_amdgcn_exp2f(sc[mi][sj][r]);
#pragma unroll
                for (int g = 0; g < 2; ++g) {
                    u32x4 pk;
                    pk[0] = cvtpk(ex[2 * g][0],     ex[2 * g][1]);
                    pk[1] = cvtpk(ex[2 * g][2],     ex[2 * g][3]);
                    pk[2] = cvtpk(ex[2 * g + 1][0], ex[2 * g + 1][1]);
                    pk[3] = cvtpk(ex[2 * g + 1][2], ex[2 * g + 1][3]);
                    ap[mi][g] = __builtin_bit_cast(s16x8, pk);
                }
            }

            s16x8 vf[4][2];
#pragma unroll
            for (int nt = 0; nt < 4; ++nt)
#pragma unroll
                for (int g = 0; g < 2; ++g)
                    vf[nt][g] = *(const s16x8*)&Vb[(nt * 2 + g) * 512 + l * 8];

            __builtin_amdgcn_s_setprio(1);
#pragma unroll
            for (int mi = 0; mi < 2; ++mi) {
                dnacc[mi] = MFMA(ap[mi][0], ones, dnacc[mi]);
                dnacc[mi] = MFMA(ap[mi][1], ones, dnacc[mi]);
            }
#pragma unroll
            for (int mi = 0; mi < 2; ++mi)
#pragma unroll
                for (int nt = 0; nt < 4; ++nt) {
                    oacc[mi][nt] = MFMA(ap[mi][0], vf[nt][0], oacc[mi][nt]);
                    oacc[mi][nt] = MFMA(ap[mi][1], vf[nt][1], oacc[mi][nt]);
                }
            __builtin_amdgcn_s_setprio(0);

            asm volatile("s_waitcnt vmcnt(0)" ::: "memory");
            __syncthreads();
        }

        // combine parity partners via LDS (reuse K/V buffers)
        float* ob = (float*)U;               // 128 q x 64 d fp32 = 32 KB
        float* db = (float*)(U + 16384);     // 128 q fp32
        if (pr == 1) {
#pragma unroll
            for (int mi = 0; mi < 2; ++mi) {
#pragma unroll
                for (int r = 0; r < 4; ++r) {
                    int ql = wq * 32 + mi * 16 + quad * 4 + r;
#pragma unroll
                    for (int nt = 0; nt < 4; ++nt)
                        ob[ql * 64 + nt * 16 + l16] = oacc[mi][nt][r];
                    if (l16 == 0) db[ql] = dnacc[mi][r];
                }
            }
        }
        __syncthreads();
        if (pr == 0) {
#pragma unroll
            for (int mi = 0; mi < 2; ++mi)
#pragma unroll
                for (int r = 0; r < 4; ++r) {
                    int ql = wq * 32 + mi * 16 + quad * 4 + r;
                    float inv = 1.0f / (dnacc[mi][r] + db[ql]);
                    int t = qrow0 + mi * 16 + quad * 4 + r;
#pragma unroll
                    for (int nt = 0; nt < 4; ++nt) {
                        float v = oacc[mi][nt][r] + ob[ql * 64 + nt * 16 + l16];
                        am[(size_t)(b * Tn + t) * Wd + h * Dh + nt * 16 + l16] = f2bf(v * inv);
                    }
                }
        }
    }
    gbar(bar);

    // ===================== P3: proj =====================
    {
        short* const AsB = U;                // [2][128*72] = 36,864 B
        short* const BsB = U + 18432;        // [2][64*72]  = 18,432 B

        const int bn = bid & 15;             // 16 n-tiles
        const int bm = bid >> 4;             // 32 m-tiles
        const int m0 = bm * 128;
        const int n0 = bn * 64;
        const int wm = (w & 3) * 32;         // wave m-offset (4 m-waves)
        const int wn = (w >> 2) * 32;        // wave n-offset (2 n-waves)

        const int rr = tid >> 3;             // staging row 0..63
        const int sg = tid & 7;              // 16B segment 0..7 (BK=64)

        f32x4 acc[2][2];
#pragma unroll
        for (int mi = 0; mi < 2; ++mi)
#pragma unroll
            for (int nt = 0; nt < 2; ++nt) {
                acc[mi][nt][0] = 0.f; acc[mi][nt][1] = 0.f;
                acc[mi][nt][2] = 0.f; acc[mi][nt][3] = 0.f;
            }

        // prologue: stage k-chunk 0 into buffer 0
        s16x8 ra0 = ld8(am + (size_t)(m0 + rr) * Wd + sg * 8);
        s16x8 ra1 = ld8(am + (size_t)(m0 + 64 + rr) * Wd + sg * 8);
        s16x8 rb  = ld8(wb + (size_t)(n0 + rr) * Wd + sg * 8);
        *(s16x8*)&AsB[rr * 72 + sg * 8]        = ra0;
        *(s16x8*)&AsB[(rr + 64) * 72 + sg * 8] = ra1;
        *(s16x8*)&BsB[rr * 72 + sg * 8]        = rb;
        __syncthreads();

        for (int k0 = 0; k0 < Wd; k0 += 64) {
            const int p = (k0 >> 6) & 1;
            short* Asp = AsB + p * 9216;
            short* Bsp = BsB + p * 4608;

            if (k0 + 64 < Wd) {
                ra0 = ld8(am + (size_t)(m0 + rr) * Wd + k0 + 64 + sg * 8);
                ra1 = ld8(am + (size_t)(m0 + 64 + rr) * Wd + k0 + 64 + sg * 8);
                rb  = ld8(wb + (size_t)(n0 + rr) * Wd + k0 + 64 + sg * 8);
            }

            s16x8 a[2][2], bw[2][2];
#pragma unroll
            for (int mi = 0; mi < 2; ++mi)
#pragma unroll
                for (int ks = 0; ks < 2; ++ks)
                    a[mi][ks] = *(const s16x8*)&Asp[(wm + mi * 16 + l16) * 72 + ks * 32 + quad * 8];
#pragma unroll
            for (int nt = 0; nt < 2; ++nt)
#pragma unroll
                for (int ks = 0; ks < 2; ++ks)
                    bw[nt][ks] = *(const s16x8*)&Bsp[(wn + nt * 16 + l16) * 72 + ks * 32 + quad * 8];

            __builtin_amdgcn_s_setprio(1);
#pragma unroll
            for (int mi = 0; mi < 2; ++mi)
#pragma unroll
                for (int nt = 0; nt < 2; ++nt) {
                    acc[mi][nt] = MFMA(a[mi][0], bw[nt][0], acc[mi][nt]);
                    acc[mi][nt] = MFMA(a[mi][1], bw[nt][1], acc[mi][nt]);
                }
            __builtin_amdgcn_s_setprio(0);

            if (k0 + 64 < Wd) {
                short* Asn = AsB + (p ^ 1) * 9216;
                short* Bsn = BsB + (p ^ 1) * 4608;
                *(s16x8*)&Asn[rr * 72 + sg * 8]        = ra0;
                *(s16x8*)&Asn[(rr + 64) * 72 + sg * 8] = ra1;
                *(s16x8*)&Bsn[rr * 72 + sg * 8]        = rb;
            }
            __syncthreads();
        }

#pragma unroll
        for (int nt = 0; nt < 2; ++nt) {
            float bv = bias[n0 + wn + nt * 16 + l16];
#pragma unroll
            for (int mi = 0; mi < 2; ++mi)
#pragma unroll
                for (int r = 0; r < 4; ++r)
                    out[(size_t)(m0 + wm + mi * 16 + quad * 4 + r) * Wd + n0 + wn + nt * 16 + l16] =
                        acc[mi][nt][r] + bv;
        }
    }
}

extern "C" void kernel_launch(void* const* d_in, const int* in_sizes, int n_in,
                              void* d_out, int out_size, void* d_ws, size_t ws_size,
                              hipStream_t stream) {
    const float* x  = (const float*)d_in[0];   // [2,2048,1024] fp32
    const float* ck = (const float*)d_in[1];   // [2,2048,1024] fp32
    const float* cv = (const float*)d_in[2];   // [2,2048,1024] fp32
    const float* wp = (const float*)d_in[3];   // [1024,1024]   fp32
    const float* bp = (const float*)d_in[4];   // [1024]        fp32

    const int nX = Bn * Tn * Wd;   // 4,194,304
    const int nW = Wd * Wd;        // 1,048,576

    short* kpb = (short*)d_ws;     // 8 MB  (K, MFMA A-frag packed)
    short* vpb = kpb + nX;         // 8 MB  (V^T, MFMA B-frag packed + s-perm)
    short* wbb = vpb + nX;         // 2 MB  (Wp bf16, row-major)
    short* amb = wbb + nW;         // 8 MB  (attention output, bf16)
    unsigned* bar = (unsigned*)(amb + nX);   // 8 B barrier state
    float* op  = (float*)d_out;

    binit<<<dim3(1), dim3(1), 0, stream>>>(bar);
    fused<<<dim3(NBLK), dim3(512), 0, stream>>>(
        x, ck, cv, wp, bp, kpb, vpb, wbb, amb, op, bar);
}

// Round 14
// 248.792 us; speedup vs baseline: 1.5582x; 1.1688x over previous
//
#include <hip/hip_runtime.h>

#define Bn 2
#define Hn 16
#define Tn 2048
#define Sn 2048
#define Wd 1024
#define Dh 64
#define NBLK 512

typedef __attribute__((ext_vector_type(8))) short s16x8;
typedef __attribute__((ext_vector_type(4))) short s16x4;
typedef __attribute__((ext_vector_type(4))) float f32x4;
typedef __attribute__((ext_vector_type(4))) unsigned u32x4;

#define MFMA(a, b, c) __builtin_amdgcn_mfma_f32_16x16x32_bf16((a), (b), (c), 0, 0, 0)

__device__ __forceinline__ s16x8 ld8(const short* p) { return *(const s16x8*)p; }

// fp32 -> bf16 round-to-nearest-even
__device__ __forceinline__ short f2bf(float f) {
    unsigned u = __builtin_bit_cast(unsigned, f);
    u += 0x7FFFu + ((u >> 16) & 1u);
    return (short)(u >> 16);
}

// pack 2 f32 -> 2 bf16 (RNE) in one instruction
__device__ __forceinline__ unsigned cvtpk(float lo, float hi) {
    unsigned r;
    asm("v_cvt_pk_bf16_f32 %0, %1, %2" : "=v"(r) : "v"(lo), "v"(hi));
    return r;
}

// async global->LDS, 16B/lane: LDS dest = wave-uniform base + lane*16
__device__ __forceinline__ void gl_lds(const short* g, short* lds) {
    __builtin_amdgcn_global_load_lds(
        (const __attribute__((address_space(1))) void*)g,
        (__attribute__((address_space(3))) void*)lds, 16, 0, 0);
}

// Barrier state init (runs just before fused on the same stream).
__global__ void binit(unsigned* bar) { bar[0] = 0u; bar[1] = 0u; }

// Co-resident grid barrier, R14: NO acquire-side cache invalidate.
// R13's trailing acquire fence ran on EVERY WAVE (8192 buffer_inv = full
// XCD L1+L2 invalidates per kernel) -> ~110us serialized at the 8 L2s
// (R13: MfmaUtil 9%, 85% idle).  Coherence audit shows the inv is
// unnecessary for THIS dataflow: an XCD L2 can only hold lines of
// kp/vp/wb/am that blocks on that XCD wrote THIS execution (fresh), or
// none (dispatch-begin acquire cleaned L2; no phase reads an address
// before its producer phase).  CDNA L1 is a write-through read cache and
// no CU re-reads its own writes across a phase.  What IS required:
// producers' dirty L2 lines must reach the device-coherent L3 before the
// generation bump -- the per-block release fence (s_waitcnt +
// buffer_wbl2) provides exactly that, mapping-independently (the last
// arrival per XCD writes back everything).  Spin loads are RELAXED
// (plain, no cache ops).  Bounded spin -> fails visibly, never hangs.
__device__ __forceinline__ void gbar(unsigned* bar) {
    __syncthreads();
    if (threadIdx.x == 0) {
        __builtin_amdgcn_fence(__ATOMIC_RELEASE, "agent");   // waitcnt + wbl2
        unsigned g = __hip_atomic_load(&bar[1], __ATOMIC_RELAXED,
                                       __HIP_MEMORY_SCOPE_AGENT);
        unsigned arr = __hip_atomic_fetch_add(&bar[0], 1u, __ATOMIC_RELAXED,
                                              __HIP_MEMORY_SCOPE_AGENT);
        if (arr == NBLK - 1u) {
            __hip_atomic_store(&bar[0], 0u, __ATOMIC_RELAXED,
                               __HIP_MEMORY_SCOPE_AGENT);
            __hip_atomic_store(&bar[1], g + 1u, __ATOMIC_RELEASE,
                               __HIP_MEMORY_SCOPE_AGENT);
        } else {
            long spins = 0;
            while (__hip_atomic_load(&bar[1], __ATOMIC_RELAXED,
                                     __HIP_MEMORY_SCOPE_AGENT) == g) {
                __builtin_amdgcn_s_sleep(2);
                if (++spins > (1L << 24)) break;   // fail visibly, never hang
            }
        }
    }
    __syncthreads();
    __asm__ __volatile__("" ::: "memory");   // compiler-only ordering; no inv
}

// ---------------------------------------------------------------------------
// Single fused kernel: prep -> gbar -> attn -> gbar -> proj.
// Grid 512 x 512 thr, 64KB LDS union, launch_bounds(512,4) -> exactly
// 2 blocks/CU co-resident (16 waves/CU).  Phase bodies are byte-identical
// to the R8 bench-verified kernels.
// ---------------------------------------------------------------------------
__global__ __launch_bounds__(512, 4) void fused(
    const float* __restrict__ x,  const float* __restrict__ ck,
    const float* __restrict__ cv, const float* __restrict__ wp,
    const float* __restrict__ bias,
    short* __restrict__ kp, short* __restrict__ vp, short* __restrict__ wb,
    short* __restrict__ am, float* __restrict__ out, unsigned* __restrict__ bar)
{
    __shared__ alignas(16) short U[32768];   // 64 KB union for all phases

    const int tid  = threadIdx.x;
    const int bid  = blockIdx.x;
    const int w    = tid >> 6;               // 0..7
    const int l    = tid & 63;
    const int quad = l >> 4;
    const int l16  = l & 15;

    // ===================== P1: prep =====================
    for (int task = bid; task < 2304; task += 512) {
        __syncthreads();                     // protect U reuse across tasks
        if (task < 2048) {
            const int isV = task >> 10;      // 0 = kpack, 1 = vpack
            const int c   = task & 1023;
            const int bh = c >> 5, sc = c & 31;
            const int b = bh >> 4, h = bh & 15;
            const float* src = (isV ? cv : ck) + (size_t)(b * Sn + sc * 64) * Wd + h * Dh;
#pragma unroll
            for (int i = 0; i < 2; ++i) {
                int f = i * 512 + tid, sr = f >> 4, c4 = f & 15;
                float4 v = *(const float4*)(src + (size_t)sr * Wd + c4 * 4);
                s16x4 o;
                o[0] = f2bf(v.x); o[1] = f2bf(v.y); o[2] = f2bf(v.z); o[3] = f2bf(v.w);
                *(s16x4*)&U[sr * 72 + c4 * 4] = o;
            }
            __syncthreads();
            if (tid < 256) {
                const int rt = tid >> 6;     // 0..3
                if (!isV) {
                    size_t base = ((size_t)((bh * 128 + sc * 4 + rt) * 2)) * 512 + l * 8;
                    *(s16x8*)(kp + base)       = *(const s16x8*)&U[(rt * 16 + l16) * 72 + quad * 8];
                    *(s16x8*)(kp + base + 512) = *(const s16x8*)&U[(rt * 16 + l16) * 72 + 32 + quad * 8];
                } else {
#pragma unroll
                    for (int g = 0; g < 2; ++g) {
                        s16x8 o;
#pragma unroll
                        for (int j = 0; j < 8; ++j) {
                            int s = 32 * g + 16 * (j >> 2) + quad * 4 + (j & 3);
                            o[j] = U[s * 72 + rt * 16 + l16];
                        }
                        *(s16x8*)(vp + ((size_t)((bh * 32 + sc) * 8 + rt * 2 + g)) * 512 + l * 8) = o;
                    }
                }
            }
        } else {
            int i = ((task - 2048) * 512 + tid) * 8;
            float4 a = *(const float4*)(wp + i);
            float4 b2 = *(const float4*)(wp + i + 4);
            s16x8 o;
            o[0] = f2bf(a.x); o[1] = f2bf(a.y); o[2] = f2bf(a.z); o[3] = f2bf(a.w);
            o[4] = f2bf(b2.x); o[5] = f2bf(b2.y); o[6] = f2bf(b2.z); o[7] = f2bf(b2.w);
            *(s16x8*)(wb + i) = o;
        }
    }
    gbar(bar);

    // ===================== P2: attn =====================
    {
        short* const KsB = U;                // [sb*2+pr][4096] (32 KB)
        short* const VsB = U + 16384;        // [sb*2+pr][4096] (32 KB)

        const int wq = w & 3;                // q subtile (32 rows)
        const int pr = w >> 2;               // s parity

        const int bh = bid & 31;             // blk%8 = bh%8 -> XCD locality
        const int qt = bid >> 5;
        const int b  = bh >> 4, h = bh & 15;

        const int qrow0 = qt * 128 + wq * 32;

        const short* kp_h = kp + (size_t)bh * 131072;
        const short* vp_h = vp + (size_t)bh * 131072;

        // prologue: stage super-pair 0 (chunks 0,1) into superbuf 0
        gl_lds(kp_h + ((size_t)(0 * 8 + w)) * 512 + l * 8, KsB + 0 * 4096 + w * 512);
        gl_lds(vp_h + ((size_t)(0 * 8 + w)) * 512 + l * 8, VsB + 0 * 4096 + w * 512);
        gl_lds(kp_h + ((size_t)(1 * 8 + w)) * 512 + l * 8, KsB + 1 * 4096 + w * 512);
        gl_lds(vp_h + ((size_t)(1 * 8 + w)) * 512 + l * 8, VsB + 1 * 4096 + w * 512);

        const float SQ = 0.125f * 1.4426950408889634f;
        s16x8 aq[2][2];
#pragma unroll
        for (int mi = 0; mi < 2; ++mi)
#pragma unroll
            for (int c = 0; c < 2; ++c) {
                const float* p = x + (size_t)(b * Tn + qrow0 + mi * 16 + l16) * Wd
                                   + h * Dh + c * 32 + quad * 8;
                float4 a = ((const float4*)p)[0], bb = ((const float4*)p)[1];
                s16x8 o;
                o[0] = f2bf(a.x * SQ); o[1] = f2bf(a.y * SQ); o[2] = f2bf(a.z * SQ); o[3] = f2bf(a.w * SQ);
                o[4] = f2bf(bb.x * SQ); o[5] = f2bf(bb.y * SQ); o[6] = f2bf(bb.z * SQ); o[7] = f2bf(bb.w * SQ);
                aq[mi][c] = o;
            }

        f32x4 oacc[2][4], dnacc[2];
#pragma unroll
        for (int mi = 0; mi < 2; ++mi) {
#pragma unroll
            for (int nt = 0; nt < 4; ++nt) {
                oacc[mi][nt][0] = 0.f; oacc[mi][nt][1] = 0.f;
                oacc[mi][nt][2] = 0.f; oacc[mi][nt][3] = 0.f;
            }
            dnacc[mi][0] = 0.f; dnacc[mi][1] = 0.f;
            dnacc[mi][2] = 0.f; dnacc[mi][3] = 0.f;
        }

        s16x8 ones;
#pragma unroll
        for (int j = 0; j < 8; ++j) ones[j] = (short)0x3F80;   // bf16 1.0

        const f32x4 z = {0.f, 0.f, 0.f, 0.f};
        const int NSIT = Sn / 128;           // 16 super-iters (2 chunks each)

        asm volatile("s_waitcnt vmcnt(0)" ::: "memory");
        __syncthreads();

        for (int t = 0; t < NSIT; ++t) {
            const int sb = t & 1;

            if (t + 1 < NSIT) {
                const size_t c0 = (size_t)(2 * t + 2) * 8;
                gl_lds(kp_h + (c0 + w) * 512 + l * 8,     KsB + ((sb ^ 1) * 2 + 0) * 4096 + w * 512);
                gl_lds(vp_h + (c0 + w) * 512 + l * 8,     VsB + ((sb ^ 1) * 2 + 0) * 4096 + w * 512);
                gl_lds(kp_h + (c0 + 8 + w) * 512 + l * 8, KsB + ((sb ^ 1) * 2 + 1) * 4096 + w * 512);
                gl_lds(vp_h + (c0 + 8 + w) * 512 + l * 8, VsB + ((sb ^ 1) * 2 + 1) * 4096 + w * 512);
            }

            const short* Kb = KsB + (sb * 2 + pr) * 4096;
            const short* Vb = VsB + (sb * 2 + pr) * 4096;

            s16x8 kf[4][2];
#pragma unroll
            for (int sj = 0; sj < 4; ++sj)
#pragma unroll
                for (int g = 0; g < 2; ++g)
                    kf[sj][g] = *(const s16x8*)&Kb[(sj * 2 + g) * 512 + l * 8];

            f32x4 sc[2][4];
            __builtin_amdgcn_s_setprio(1);
#pragma unroll
            for (int sj = 0; sj < 4; ++sj)
#pragma unroll
                for (int mi = 0; mi < 2; ++mi) {
                    sc[mi][sj] = MFMA(kf[sj][0], aq[mi][0], z);
                    sc[mi][sj] = MFMA(kf[sj][1], aq[mi][1], sc[mi][sj]);
                }
            __builtin_amdgcn_s_setprio(0);

            s16x8 ap[2][2];
#pragma unroll
            for (int mi = 0; mi < 2; ++mi) {
                float ex[4][4];
#pragma unroll
                for (int sj = 0; sj < 4; ++sj)
#pragma unroll
                    for (int r = 0; r < 4; ++r)
                        ex[sj][r] = __builtin_amdgcn_exp2f(sc[mi][sj][r]);
#pragma unroll
                for (int g = 0; g < 2; ++g) {
                    u32x4 pk;
                    pk[0] = cvtpk(ex[2 * g][0],     ex[2 * g][1]);
                    pk[1] = cvtpk(ex[2 * g][2],     ex[2 * g][3]);
                    pk[2] = cvtpk(ex[2 * g + 1][0], ex[2 * g + 1][1]);
                    pk[3] = cvtpk(ex[2 * g + 1][2], ex[2 * g + 1][3]);
                    ap[mi][g] = __builtin_bit_cast(s16x8, pk);
                }
            }

            s16x8 vf[4][2];
#pragma unroll
            for (int nt = 0; nt < 4; ++nt)
#pragma unroll
                for (int g = 0; g < 2; ++g)
                    vf[nt][g] = *(const s16x8*)&Vb[(nt * 2 + g) * 512 + l * 8];

            __builtin_amdgcn_s_setprio(1);
#pragma unroll
            for (int mi = 0; mi < 2; ++mi) {
                dnacc[mi] = MFMA(ap[mi][0], ones, dnacc[mi]);
                dnacc[mi] = MFMA(ap[mi][1], ones, dnacc[mi]);
            }
#pragma unroll
            for (int mi = 0; mi < 2; ++mi)
#pragma unroll
                for (int nt = 0; nt < 4; ++nt) {
                    oacc[mi][nt] = MFMA(ap[mi][0], vf[nt][0], oacc[mi][nt]);
                    oacc[mi][nt] = MFMA(ap[mi][1], vf[nt][1], oacc[mi][nt]);
                }
            __builtin_amdgcn_s_setprio(0);

            asm volatile("s_waitcnt vmcnt(0)" ::: "memory");
            __syncthreads();
        }

        // combine parity partners via LDS (reuse K/V buffers)
        float* ob = (float*)U;               // 128 q x 64 d fp32 = 32 KB
        float* db = (float*)(U + 16384);     // 128 q fp32
        if (pr == 1) {
#pragma unroll
            for (int mi = 0; mi < 2; ++mi) {
#pragma unroll
                for (int r = 0; r < 4; ++r) {
                    int ql = wq * 32 + mi * 16 + quad * 4 + r;
#pragma unroll
                    for (int nt = 0; nt < 4; ++nt)
                        ob[ql * 64 + nt * 16 + l16] = oacc[mi][nt][r];
                    if (l16 == 0) db[ql] = dnacc[mi][r];
                }
            }
        }
        __syncthreads();
        if (pr == 0) {
#pragma unroll
            for (int mi = 0; mi < 2; ++mi)
#pragma unroll
                for (int r = 0; r < 4; ++r) {
                    int ql = wq * 32 + mi * 16 + quad * 4 + r;
                    float inv = 1.0f / (dnacc[mi][r] + db[ql]);
                    int t = qrow0 + mi * 16 + quad * 4 + r;
#pragma unroll
                    for (int nt = 0; nt < 4; ++nt) {
                        float v = oacc[mi][nt][r] + ob[ql * 64 + nt * 16 + l16];
                        am[(size_t)(b * Tn + t) * Wd + h * Dh + nt * 16 + l16] = f2bf(v * inv);
                    }
                }
        }
    }
    gbar(bar);

    // ===================== P3: proj =====================
    {
        short* const AsB = U;                // [2][128*72] = 36,864 B
        short* const BsB = U + 18432;        // [2][64*72]  = 18,432 B

        const int bn = bid & 15;             // 16 n-tiles
        const int bm = bid >> 4;             // 32 m-tiles
        const int m0 = bm * 128;
        const int n0 = bn * 64;
        const int wm = (w & 3) * 32;         // wave m-offset (4 m-waves)
        const int wn = (w >> 2) * 32;        // wave n-offset (2 n-waves)

        const int rr = tid >> 3;             // staging row 0..63
        const int sg = tid & 7;              // 16B segment 0..7 (BK=64)

        f32x4 acc[2][2];
#pragma unroll
        for (int mi = 0; mi < 2; ++mi)
#pragma unroll
            for (int nt = 0; nt < 2; ++nt) {
                acc[mi][nt][0] = 0.f; acc[mi][nt][1] = 0.f;
                acc[mi][nt][2] = 0.f; acc[mi][nt][3] = 0.f;
            }

        // prologue: stage k-chunk 0 into buffer 0
        s16x8 ra0 = ld8(am + (size_t)(m0 + rr) * Wd + sg * 8);
        s16x8 ra1 = ld8(am + (size_t)(m0 + 64 + rr) * Wd + sg * 8);
        s16x8 rb  = ld8(wb + (size_t)(n0 + rr) * Wd + sg * 8);
        *(s16x8*)&AsB[rr * 72 + sg * 8]        = ra0;
        *(s16x8*)&AsB[(rr + 64) * 72 + sg * 8] = ra1;
        *(s16x8*)&BsB[rr * 72 + sg * 8]        = rb;
        __syncthreads();

        for (int k0 = 0; k0 < Wd; k0 += 64) {
            const int p = (k0 >> 6) & 1;
            short* Asp = AsB + p * 9216;
            short* Bsp = BsB + p * 4608;

            if (k0 + 64 < Wd) {
                ra0 = ld8(am + (size_t)(m0 + rr) * Wd + k0 + 64 + sg * 8);
                ra1 = ld8(am + (size_t)(m0 + 64 + rr) * Wd + k0 + 64 + sg * 8);
                rb  = ld8(wb + (size_t)(n0 + rr) * Wd + k0 + 64 + sg * 8);
            }

            s16x8 a[2][2], bw[2][2];
#pragma unroll
            for (int mi = 0; mi < 2; ++mi)
#pragma unroll
                for (int ks = 0; ks < 2; ++ks)
                    a[mi][ks] = *(const s16x8*)&Asp[(wm + mi * 16 + l16) * 72 + ks * 32 + quad * 8];
#pragma unroll
            for (int nt = 0; nt < 2; ++nt)
#pragma unroll
                for (int ks = 0; ks < 2; ++ks)
                    bw[nt][ks] = *(const s16x8*)&Bsp[(wn + nt * 16 + l16) * 72 + ks * 32 + quad * 8];

            __builtin_amdgcn_s_setprio(1);
#pragma unroll
            for (int mi = 0; mi < 2; ++mi)
#pragma unroll
                for (int nt = 0; nt < 2; ++nt) {
                    acc[mi][nt] = MFMA(a[mi][0], bw[nt][0], acc[mi][nt]);
                    acc[mi][nt] = MFMA(a[mi][1], bw[nt][1], acc[mi][nt]);
                }
            __builtin_amdgcn_s_setprio(0);

            if (k0 + 64 < Wd) {
                short* Asn = AsB + (p ^ 1) * 9216;
                short* Bsn = BsB + (p ^ 1) * 4608;
                *(s16x8*)&Asn[rr * 72 + sg * 8]        = ra0;
                *(s16x8*)&Asn[(rr + 64) * 72 + sg * 8] = ra1;
                *(s16x8*)&Bsn[rr * 72 + sg * 8]        = rb;
            }
            __syncthreads();
        }

#pragma unroll
        for (int nt = 0; nt < 2; ++nt) {
            float bv = bias[n0 + wn + nt * 16 + l16];
#pragma unroll
            for (int mi = 0; mi < 2; ++mi)
#pragma unroll
                for (int r = 0; r < 4; ++r)
                    out[(size_t)(m0 + wm + mi * 16 + quad * 4 + r) * Wd + n0 + wn + nt * 16 + l16] =
                        acc[mi][nt][r] + bv;
        }
    }
}

extern "C" void kernel_launch(void* const* d_in, const int* in_sizes, int n_in,
                              void* d_out, int out_size, void* d_ws, size_t ws_size,
                              hipStream_t stream) {
    const float* x  = (const float*)d_in[0];   // [2,2048,1024] fp32
    const float* ck = (const float*)d_in[1];   // [2,2048,1024] fp32
    const float* cv = (const float*)d_in[2];   // [2,2048,1024] fp32
    const float* wp = (const float*)d_in[3];   // [1024,1024]   fp32
    const float* bp = (const float*)d_in[4];   // [1024]        fp32

    const int nX = Bn * Tn * Wd;   // 4,194,304
    const int nW = Wd * Wd;        // 1,048,576

    short* kpb = (short*)d_ws;     // 8 MB  (K, MFMA A-frag packed)
    short* vpb = kpb + nX;         // 8 MB  (V^T, MFMA B-frag packed + s-perm)
    short* wbb = vpb + nX;         // 2 MB  (Wp bf16, row-major)
    short* amb = wbb + nW;         // 8 MB  (attention output, bf16)
    unsigned* bar = (unsigned*)(amb + nX);   // 8 B barrier state
    float* op  = (float*)d_out;

    binit<<<dim3(1), dim3(1), 0, stream>>>(bar);
    fused<<<dim3(NBLK), dim3(512), 0, stream>>>(
        x, ck, cv, wp, bp, kpb, vpb, wbb, amb, op, bar);
}